// Round 1
// baseline (294.722 us; speedup 1.0000x reference)
//
#include <hip/hip_runtime.h>

#define BB 4
#define NN 2000
#define K_PRE 1000
#define MAXOUT 128
#define NMS_THR 0.3f
#define MIN_D 28
#define MOUT_D 32
#define MASK_IN_VOX (28*28*28)   // 21952
#define MASK_OUT_VOX (32*32*32)  // 32768

// ---------------- rank (stable descending argsort via rank counting) --------
__global__ __launch_bounds__(256) void rank_kernel(const float* __restrict__ scores,
                                                   int* __restrict__ order) {
    int b = blockIdx.x >> 3;       // 8 chunks per batch
    int chunk = blockIdx.x & 7;
    __shared__ float s[NN];
    const float* sb = scores + b * NN;
    for (int j = threadIdx.x; j < NN; j += 256) s[j] = sb[j];
    __syncthreads();
    int i = chunk * 256 + threadIdx.x;
    if (i >= NN) return;
    float si = s[i];
    int rank = 0;
#pragma unroll 4
    for (int j = 0; j < NN; ++j) {
        float sj = s[j];
        rank += (sj > si) || (sj == si && j < i);
    }
    if (rank < K_PRE) order[b * K_PRE + rank] = i;
}

// ---------------- regression + greedy NMS (one block per batch) -------------
__global__ __launch_bounds__(256) void nms_kernel(const float* __restrict__ proposals,
                                                  const float* __restrict__ deltas,
                                                  const int* __restrict__ order,
                                                  float* __restrict__ out_boxes,
                                                  float* __restrict__ out_bidx,
                                                  int* __restrict__ g_idx,
                                                  float* __restrict__ g_valid) {
    int b = blockIdx.x;
    __shared__ float y1s[K_PRE], x1s[K_PRE], z1s[K_PRE];
    __shared__ float y2s[K_PRE], x2s[K_PRE], z2s[K_PRE];
    __shared__ unsigned char sup[K_PRE];
    __shared__ int wave_min[4];
    __shared__ int chosen_s;
    int tid = threadIdx.x;

    // load selected proposals/deltas, apply 3D regression
    for (int k = tid; k < K_PRE; k += 256) {
        int i = order[b * K_PRE + k];
        const float* p = proposals + (size_t)(b * NN + i) * 6;
        const float* d = deltas    + (size_t)(b * NN + i) * 6;
        float py1 = p[0], px1 = p[1], pz1 = p[2], py2 = p[3], px2 = p[4], pz2 = p[5];
        float h = py2 - py1, w = px2 - px1, dd = pz2 - pz1;
        float cy = py1 + 0.5f * h + d[0] * h;
        float cx = px1 + 0.5f * w + d[1] * w;
        float cz = pz1 + 0.5f * dd + d[2] * dd;
        h *= expf(d[3]); w *= expf(d[4]); dd *= expf(d[5]);
        y1s[k] = cy - 0.5f * h;  x1s[k] = cx - 0.5f * w;  z1s[k] = cz - 0.5f * dd;
        y2s[k] = cy + 0.5f * h;  x2s[k] = cx + 0.5f * w;  z2s[k] = cz + 0.5f * dd;
        sup[k] = 0;
    }
    __syncthreads();

    for (int step = 0; step < MAXOUT; ++step) {
        // find first unsuppressed index (scores sorted desc => argmax == first unset)
        int local = K_PRE;
        for (int k = tid; k < K_PRE; k += 256) {
            if (!sup[k]) { local = k; break; }
        }
        for (int off = 32; off; off >>= 1) local = min(local, __shfl_down(local, off));
        if ((tid & 63) == 0) wave_min[tid >> 6] = local;
        __syncthreads();
        if (tid == 0) {
            chosen_s = min(min(wave_min[0], wave_min[1]), min(wave_min[2], wave_min[3]));
        }
        __syncthreads();
        int c = chosen_s;
        int valid = (c < K_PRE);
        int cc = valid ? c : 0;
        float by1 = y1s[cc], bx1 = x1s[cc], bz1 = z1s[cc];
        float by2 = y2s[cc], bx2 = x2s[cc], bz2 = z2s[cc];
        if (valid) {
            float v1 = (by2 - by1) * (bx2 - bx1) * (bz2 - bz1);
            for (int k = tid; k < K_PRE; k += 256) {
                if (sup[k]) continue;
                float iy = fmaxf(fminf(by2, y2s[k]) - fmaxf(by1, y1s[k]), 0.f);
                float ix = fmaxf(fminf(bx2, x2s[k]) - fmaxf(bx1, x1s[k]), 0.f);
                float iz = fmaxf(fminf(bz2, z2s[k]) - fmaxf(bz1, z1s[k]), 0.f);
                float inter = iy * ix * iz;
                float v2 = (y2s[k] - y1s[k]) * (x2s[k] - x1s[k]) * (z2s[k] - z1s[k]);
                float iou = inter / (v1 + v2 - inter + 1e-8f);
                if (iou > NMS_THR) sup[k] = 1;
            }
        }
        if (tid == 0) {
            if (valid) sup[c] = 1;   // self (IoU~1 catches it too; explicit for safety)
            float vf = valid ? 1.f : 0.f;
            g_idx[b * MAXOUT + step] = order[b * K_PRE + cc];
            g_valid[b * MAXOUT + step] = vf;
            float* ob = out_boxes + (size_t)(b * MAXOUT + step) * 6;
            ob[0] = by1 * vf; ob[1] = bx1 * vf; ob[2] = bz1 * vf;
            ob[3] = by2 * vf; ob[4] = bx2 * vf; ob[5] = bz2 * vf;
        }
        __syncthreads();
    }
    if (tid < MAXOUT) out_bidx[b * MAXOUT + tid] = (float)b;
}

// ---------------- mask gather + trilinear 28^3 -> 32^3 ----------------------
__global__ __launch_bounds__(256) void resize_kernel(const float* __restrict__ masks,
                                                     const int* __restrict__ g_idx,
                                                     const float* __restrict__ g_valid,
                                                     float* __restrict__ out_masks) {
    int s = blockIdx.x;          // 0..B*MAXOUT-1
    int b = s >> 7;              // /MAXOUT
    int gi = g_idx[s];
    float vf = g_valid[s];
    const float* src = masks + (size_t)(b * NN + gi) * MASK_IN_VOX;
    float* dst = out_masks + (size_t)s * MASK_OUT_VOX;

    for (int v = threadIdx.x; v < MASK_OUT_VOX; v += 256) {
        int ox = v & 31, oy = (v >> 5) & 31, oz = v >> 10;
        // half-pixel-center source coords; clamped-index linear == jax normalized weights
        float sx = 0.875f * ox - 0.0625f;
        float sy = 0.875f * oy - 0.0625f;
        float sz = 0.875f * oz - 0.0625f;
        int flx = (int)floorf(sx), fly = (int)floorf(sy), flz = (int)floorf(sz);
        float fx = sx - flx, fy = sy - fly, fz = sz - flz;
        int x0 = max(0, min(27, flx)),     y0 = max(0, min(27, fly)),     z0 = max(0, min(27, flz));
        int x1 = max(0, min(27, flx + 1)), y1 = max(0, min(27, fly + 1)), z1 = max(0, min(27, flz + 1));

        const float* pz0y0 = src + (z0 * 28 + y0) * 28;
        const float* pz0y1 = src + (z0 * 28 + y1) * 28;
        const float* pz1y0 = src + (z1 * 28 + y0) * 28;
        const float* pz1y1 = src + (z1 * 28 + y1) * 28;
        float v000 = pz0y0[x0], v001 = pz0y0[x1];
        float v010 = pz0y1[x0], v011 = pz0y1[x1];
        float v100 = pz1y0[x0], v101 = pz1y0[x1];
        float v110 = pz1y1[x0], v111 = pz1y1[x1];

        float c00 = v000 + fx * (v001 - v000);
        float c01 = v010 + fx * (v011 - v010);
        float c10 = v100 + fx * (v101 - v100);
        float c11 = v110 + fx * (v111 - v110);
        float c0 = c00 + fy * (c01 - c00);
        float c1 = c10 + fy * (c11 - c10);
        float r = c0 + fz * (c1 - c0);
        dst[v] = r * vf;
    }
}

extern "C" void kernel_launch(void* const* d_in, const int* in_sizes, int n_in,
                              void* d_out, int out_size, void* d_ws, size_t ws_size,
                              hipStream_t stream) {
    const float* proposals = (const float*)d_in[0];
    const float* scores    = (const float*)d_in[1];
    const float* deltas    = (const float*)d_in[2];
    const float* masks     = (const float*)d_in[3];

    float* out = (float*)d_out;
    float* out_boxes = out;                                              // [512,6]
    float* out_masks = out + (size_t)BB * MAXOUT * 6;                    // [512,32768]
    float* out_bidx  = out + (size_t)BB * MAXOUT * 6 + (size_t)BB * MAXOUT * MASK_OUT_VOX;

    char* ws = (char*)d_ws;
    int*   order   = (int*)ws;                                           // B*1000
    int*   g_idx   = (int*)(ws + BB * K_PRE * sizeof(int));              // B*128
    float* g_valid = (float*)(ws + BB * K_PRE * sizeof(int) + BB * MAXOUT * sizeof(int));

    rank_kernel<<<BB * 8, 256, 0, stream>>>(scores, order);
    nms_kernel<<<BB, 256, 0, stream>>>(proposals, deltas, order, out_boxes, out_bidx, g_idx, g_valid);
    resize_kernel<<<BB * MAXOUT, 256, 0, stream>>>(masks, g_idx, g_valid, out_masks);
}

// Round 2
// 119.390 us; speedup vs baseline: 2.4686x; 2.4686x over previous
//
#include <hip/hip_runtime.h>
#include <stdint.h>

#define BB 4
#define NN 2000
#define K_PRE 1000
#define KPAD 1024
#define MAXOUT 128
#define NMS_THR 0.3f
#define MASK_IN_VOX (28*28*28)   // 21952
#define MASK_OUT_VOX (32*32*32)  // 32768

// ---------------- rank (stable descending argsort) + regression -------------
// thread i computes rank of score i; if rank < 1000 it writes order[rank] and
// the regressed box (SoA [6][1024]) directly.
__global__ __launch_bounds__(256) void rank_kernel(const float* __restrict__ scores,
                                                   const float* __restrict__ proposals,
                                                   const float* __restrict__ deltas,
                                                   int* __restrict__ order,
                                                   float* __restrict__ boxes_ws) {
    int b = blockIdx.x >> 3;       // 8 chunks per batch
    int chunk = blockIdx.x & 7;
    __shared__ float s[NN];
    const float* sb = scores + b * NN;
    for (int j = threadIdx.x; j < NN; j += 256) s[j] = sb[j];
    __syncthreads();
    int i = chunk * 256 + threadIdx.x;
    if (i >= NN) return;
    float si = s[i];
    int rank = 0;
#pragma unroll 4
    for (int j = 0; j < NN; ++j) {
        float sj = s[j];
        rank += (sj > si) || (sj == si && j < i);
    }
    if (rank >= K_PRE) return;
    order[b * KPAD + rank] = i;
    const float* p = proposals + (size_t)(b * NN + i) * 6;
    const float* d = deltas    + (size_t)(b * NN + i) * 6;
    float py1 = p[0], px1 = p[1], pz1 = p[2], py2 = p[3], px2 = p[4], pz2 = p[5];
    float h = py2 - py1, w = px2 - px1, dd = pz2 - pz1;
    float cy = py1 + 0.5f * h + d[0] * h;
    float cx = px1 + 0.5f * w + d[1] * w;
    float cz = pz1 + 0.5f * dd + d[2] * dd;
    h *= expf(d[3]); w *= expf(d[4]); dd *= expf(d[5]);
    float* bw = boxes_ws + (size_t)b * 6 * KPAD + rank;
    bw[0 * KPAD] = cy - 0.5f * h;  bw[1 * KPAD] = cx - 0.5f * w;  bw[2 * KPAD] = cz - 0.5f * dd;
    bw[3 * KPAD] = cy + 0.5f * h;  bw[4 * KPAD] = cx + 0.5f * w;  bw[5 * KPAD] = cz + 0.5f * dd;
}

// ---------------- suppression bit-matrix build ------------------------------
// maskT[b][l][r] (uint16): bit j of word l in row r  <=>  IoU(box r, box 16l+j) > thr
// (transposed layout: contiguous in r for the walk kernel's per-lane loads)
__global__ __launch_bounds__(256) void build_kernel(const float* __restrict__ boxes_ws,
                                                    unsigned short* __restrict__ maskT) {
    int b = blockIdx.y;
    int rowbase = blockIdx.x * 16;
    __shared__ float sb[6][1088];      // padded: index k + (k>>4) -> conflict-free stride-17
    int tid = threadIdx.x;
    const float* bw = boxes_ws + (size_t)b * 6 * KPAD;
    for (int k = tid; k < KPAD; k += 256) {
        int ks = k + (k >> 4);
#pragma unroll
        for (int c = 0; c < 6; ++c) sb[c][ks] = bw[c * KPAD + k];
    }
    __syncthreads();
    int l = tid & 63, lr = tid >> 6;
#pragma unroll
    for (int pss = 0; pss < 4; ++pss) {
        int r = rowbase + pss * 4 + lr;          // max 1007 < 1024
        int rs = r + (r >> 4);
        float ry1 = sb[0][rs], rx1 = sb[1][rs], rz1 = sb[2][rs];
        float ry2 = sb[3][rs], rx2 = sb[4][rs], rz2 = sb[5][rs];
        float v1 = (ry2 - ry1) * (rx2 - rx1) * (rz2 - rz1);
        uint32_t bits = 0;
#pragma unroll
        for (int j = 0; j < 16; ++j) {
            int ks = 17 * l + j;                 // (16l+j) + ((16l+j)>>4)
            float y1 = sb[0][ks], x1 = sb[1][ks], z1 = sb[2][ks];
            float y2 = sb[3][ks], x2 = sb[4][ks], z2 = sb[5][ks];
            float iy = fmaxf(fminf(ry2, y2) - fmaxf(ry1, y1), 0.f);
            float ix = fmaxf(fminf(rx2, x2) - fmaxf(rx1, x1), 0.f);
            float iz = fmaxf(fminf(rz2, z2) - fmaxf(rz1, z1), 0.f);
            float inter = iy * ix * iz;
            float v2 = (y2 - y1) * (x2 - x1) * (z2 - z1);
            float iou = inter / (v1 + v2 - inter + 1e-8f);
            bits |= (iou > NMS_THR ? 1u : 0u) << j;
        }
        maskT[((size_t)(b * 64 + l) << 10) + r] = (unsigned short)bits;
    }
}

// ---------------- serial greedy walk (1 wave per batch) ---------------------
__global__ __launch_bounds__(64) void walk_kernel(const unsigned short* __restrict__ maskT,
                                                  const int* __restrict__ order,
                                                  const float* __restrict__ boxes_ws,
                                                  float* __restrict__ out_boxes,
                                                  float* __restrict__ out_bidx,
                                                  int* __restrict__ g_idx,
                                                  float* __restrict__ g_valid) {
    int b = blockIdx.x;
    int lane = threadIdx.x;
    __shared__ short sel_k[MAXOUT];
    // lane l owns suppressed bits for boxes [16l, 16l+16); pre-suppress pad rows >= 1000
    uint32_t sup = (lane == 62) ? 0xFF00u : (lane == 63) ? 0xFFFFu : 0u;
    int nsel = 0;

    const uint4* gbase = (const uint4*)(maskT + (((size_t)(b * 64 + lane)) << 10));

    auto proc = [&](const uint4& buf, int g) {
        int owner = g >> 1;                      // all 8 rows of a group live in one lane's byte
        int sh = (g & 1) * 8;
        uint32_t grp = ((uint32_t)__shfl((int)sup, owner) >> sh) & 0xFFu;
        if (grp == 0xFFu) return;                // whole group already suppressed
#pragma unroll
        for (int j = 0; j < 8; ++j) {
            if (nsel >= MAXOUT) break;
            if (!((grp >> j) & 1u)) {            // row k unsuppressed -> select it
                uint32_t w = ((const uint32_t*)&buf)[j >> 1];
                uint32_t half = (j & 1) ? (w >> 16) : (w & 0xFFFFu);
                if (lane == 0) sel_k[nsel] = (short)(8 * g + j);
                sup |= half;
                grp |= ((uint32_t)__shfl((int)half, owner) >> sh) & 0xFFu;
                nsel++;
            }
        }
    };

    uint4 A = gbase[0], B = gbase[1], C = gbase[2], D = gbase[3];
    for (int g = 0; g < 128; g += 4) {
        proc(A, g);     A = gbase[min(g + 4, 127)];
        if (nsel >= MAXOUT) break;
        proc(B, g + 1); B = gbase[min(g + 5, 127)];
        if (nsel >= MAXOUT) break;
        proc(C, g + 2); C = gbase[min(g + 6, 127)];
        if (nsel >= MAXOUT) break;
        proc(D, g + 3); D = gbase[min(g + 7, 127)];
        if (nsel >= MAXOUT) break;
    }

    __builtin_amdgcn_s_waitcnt(0);  // ensure lane0's LDS writes visible (same wave; cheap)
    const float* bw = boxes_ws + (size_t)b * 6 * KPAD;
#pragma unroll
    for (int s0 = 0; s0 < 2; ++s0) {
        int s = lane + s0 * 64;
        int valid = s < nsel;
        int k = valid ? (int)sel_k[s] : 0;
        int idx = valid ? order[b * KPAD + k] : 0;
        float vf = valid ? 1.f : 0.f;
        g_idx[b * MAXOUT + s] = idx;
        g_valid[b * MAXOUT + s] = vf;
        float* ob = out_boxes + (size_t)(b * MAXOUT + s) * 6;
#pragma unroll
        for (int c = 0; c < 6; ++c) ob[c] = bw[c * KPAD + k] * vf;
        out_bidx[b * MAXOUT + s] = (float)b;
    }
}

// ---------------- mask gather + trilinear 28^3 -> 32^3 ----------------------
__global__ __launch_bounds__(256) void resize_kernel(const float* __restrict__ masks,
                                                     const int* __restrict__ g_idx,
                                                     const float* __restrict__ g_valid,
                                                     float* __restrict__ out_masks) {
    int s = blockIdx.x;          // 0..B*MAXOUT-1
    int b = s >> 7;
    int gi = g_idx[s];
    float vf = g_valid[s];
    const float* src = masks + (size_t)(b * NN + gi) * MASK_IN_VOX;
    float* dst = out_masks + (size_t)s * MASK_OUT_VOX;

    for (int v = threadIdx.x; v < MASK_OUT_VOX; v += 256) {
        int ox = v & 31, oy = (v >> 5) & 31, oz = v >> 10;
        float sx = 0.875f * ox - 0.0625f;
        float sy = 0.875f * oy - 0.0625f;
        float sz = 0.875f * oz - 0.0625f;
        int flx = (int)floorf(sx), fly = (int)floorf(sy), flz = (int)floorf(sz);
        float fx = sx - flx, fy = sy - fly, fz = sz - flz;
        int x0 = max(0, min(27, flx)),     y0 = max(0, min(27, fly)),     z0 = max(0, min(27, flz));
        int x1 = max(0, min(27, flx + 1)), y1 = max(0, min(27, fly + 1)), z1 = max(0, min(27, flz + 1));

        const float* pz0y0 = src + (z0 * 28 + y0) * 28;
        const float* pz0y1 = src + (z0 * 28 + y1) * 28;
        const float* pz1y0 = src + (z1 * 28 + y0) * 28;
        const float* pz1y1 = src + (z1 * 28 + y1) * 28;
        float v000 = pz0y0[x0], v001 = pz0y0[x1];
        float v010 = pz0y1[x0], v011 = pz0y1[x1];
        float v100 = pz1y0[x0], v101 = pz1y0[x1];
        float v110 = pz1y1[x0], v111 = pz1y1[x1];

        float c00 = v000 + fx * (v001 - v000);
        float c01 = v010 + fx * (v011 - v010);
        float c10 = v100 + fx * (v101 - v100);
        float c11 = v110 + fx * (v111 - v110);
        float c0 = c00 + fy * (c01 - c00);
        float c1 = c10 + fy * (c11 - c10);
        float r = c0 + fz * (c1 - c0);
        dst[v] = r * vf;
    }
}

extern "C" void kernel_launch(void* const* d_in, const int* in_sizes, int n_in,
                              void* d_out, int out_size, void* d_ws, size_t ws_size,
                              hipStream_t stream) {
    const float* proposals = (const float*)d_in[0];
    const float* scores    = (const float*)d_in[1];
    const float* deltas    = (const float*)d_in[2];
    const float* masks     = (const float*)d_in[3];

    float* out = (float*)d_out;
    float* out_boxes = out;                                              // [512,6]
    float* out_masks = out + (size_t)BB * MAXOUT * 6;                    // [512,32768]
    float* out_bidx  = out + (size_t)BB * MAXOUT * 6 + (size_t)BB * MAXOUT * MASK_OUT_VOX;

    char* ws = (char*)d_ws;
    int*            order    = (int*)(ws);                               // 16 KB
    int*            g_idx    = (int*)(ws + (16 << 10));                  // 2 KB
    float*          g_valid  = (float*)(ws + (18 << 10));                // 2 KB
    float*          boxes_ws = (float*)(ws + (20 << 10));                // 96 KB
    unsigned short* maskT    = (unsigned short*)(ws + (116 << 10));      // 512 KB

    rank_kernel<<<BB * 8, 256, 0, stream>>>(scores, proposals, deltas, order, boxes_ws);
    build_kernel<<<dim3(63, BB), 256, 0, stream>>>(boxes_ws, maskT);
    walk_kernel<<<BB, 64, 0, stream>>>(maskT, order, boxes_ws, out_boxes, out_bidx, g_idx, g_valid);
    resize_kernel<<<BB * MAXOUT, 256, 0, stream>>>(masks, g_idx, g_valid, out_masks);
}